// Round 11
// baseline (307.480 us; speedup 1.0000x reference)
//
#include <hip/hip_runtime.h>
#include <hip/hip_bf16.h>

// Self-attention: q=X@Wq.T+bq, k=..., v=...; S = causal_softmax(q k^T / 32); O = S v
// B=4, S=2048, D_IN=D_OUT=1024. fp32 in/out; internal compute bf16 MFMA + fp32 acc.
//
// R11 change: scores/pv cores go BK=32 -> BK=64 while KEEPING the R9 2-wave
// concurrency recipe. 32 MFMA/wave/barrier (2x), barrier count halved, grids
// unchanged (1088/1024 blocks, >=4 blocks/CU; 24 KB LDS, ~130 regs allow 6).
// R8 proved BK=64 itself is sound (0 bank conflicts) and failed only on grid
// starvation (2.1 blocks/CU); R9 proved concurrency dominates. LDS uses R8's
// measured-zero-conflict striped layout: 8-row stripes, colchunk-major
// (elem (m,k) at (m>>3)*512 + (k>>3)*64 + (m&7)*8 + (k&7)).
// qkv (R4 form, 780 TF), convert, compact grids, ones-MFMA row sums unchanged.
//
// MFMA fragment layouts (HW-verified per guide §3):
//  A: lane holds A[m=lane&15][k=(lane>>4)*8+j], j=0..7
//  B: lane holds B[k=(lane>>4)*8+j][n=lane&15]
//  C/D: lane holds D[row=(lane>>4)*4+e][col=lane&15], e=0..3

typedef __attribute__((ext_vector_type(8))) short short8;   // 8 bf16 = 4 VGPRs
typedef __attribute__((ext_vector_type(4))) float floatx4;  // MFMA acc

#define SEQ   2048
#define DMODEL 1024
#define NBATCH 4
#define MTOT  (SEQ * NBATCH)

// Direct global->LDS async copy, 16B per lane. LDS dst is wave-uniform base +
// lane*16 (per-lane scatter NOT supported).
__device__ __forceinline__ void stage16(const __hip_bfloat16* g, __hip_bfloat16* l)
{
  __builtin_amdgcn_global_load_lds(
      (const __attribute__((address_space(1))) void*)g,
      (__attribute__((address_space(3))) void*)l, 16, 0, 0);
}

__device__ __forceinline__ unsigned short bf16_bits(float f)
{
  __hip_bfloat16 h = __float2bfloat16(f);
  return *(unsigned short*)&h;
}

// ---------------------------------------------------------------------------
// One-kernel fp32 -> bf16 convert for all four inputs. Each block: 1024 elems.
__global__ __launch_bounds__(256) void convert_all(
    const float* __restrict__ X,  const float* __restrict__ Wq,
    const float* __restrict__ Wk, const float* __restrict__ Wv,
    __hip_bfloat16* __restrict__ Xb,  __hip_bfloat16* __restrict__ Wqb,
    __hip_bfloat16* __restrict__ Wkb, __hip_bfloat16* __restrict__ Wvb)
{
  const int b = blockIdx.x;
  const float* src; __hip_bfloat16* dst; int rel;
  if (b < 8192)       { src = X;  dst = Xb;  rel = b; }
  else if (b < 9216)  { src = Wq; dst = Wqb; rel = b - 8192; }
  else if (b < 10240) { src = Wk; dst = Wkb; rel = b - 9216; }
  else                { src = Wv; dst = Wvb; rel = b - 10240; }
  const int i = rel * 1024 + threadIdx.x * 4;
  float4 f = *(const float4*)(src + i);
  uint2 o;
  o.x = (unsigned)bf16_bits(f.x) | ((unsigned)bf16_bits(f.y) << 16);
  o.y = (unsigned)bf16_bits(f.z) | ((unsigned)bf16_bits(f.w) << 16);
  *(uint2*)(dst + i) = o;
}

// ---------------------------------------------------------------------------
// Fused QKV projection (R4 version, best measured). A-tile (X) staged once per
// k-iter, three 128x32 B-tiles; 48 MFMA/wave/barrier. Q,K row-major; V -> Vt.
// grid = (8, 64), 256 threads, 32 KB LDS.
__global__ __launch_bounds__(256, 2) void gemm_qkv_fused(
    const __hip_bfloat16* __restrict__ Xb,
    const __hip_bfloat16* __restrict__ Wqb,
    const __hip_bfloat16* __restrict__ Wkb,
    const __hip_bfloat16* __restrict__ Wvb,
    const float* __restrict__ bq, const float* __restrict__ bk, const float* __restrict__ bv,
    __hip_bfloat16* __restrict__ Qb, __hip_bfloat16* __restrict__ Kb, __hip_bfloat16* __restrict__ Vt)
{
  __shared__ __hip_bfloat16 As[128 * 32];
  __shared__ __hip_bfloat16 Bs[3][128 * 32];
  const int m0 = blockIdx.y * 128, n0 = blockIdx.x * 128;
  const int tid  = threadIdx.x;
  const int lane = tid & 63;
  const int wave = tid >> 6;
  const int quad = lane >> 4;
  const int r    = lane & 15;
  const int wm   = (wave >> 1) * 64;
  const int wn   = (wave & 1) * 64;
  const int srow = wave * 16 + (lane >> 2);   // 0..63
  const int scol = (lane & 3) * 8;            // 0,8,16,24

  const __hip_bfloat16* Wp[3] = {Wqb, Wkb, Wvb};

  __hip_bfloat16* lA0 = As + wave * 512;
  __hip_bfloat16* lA1 = As + 2048 + wave * 512;

  const __hip_bfloat16* aR0 = Xb + (size_t)(m0 + srow) * DMODEL + scol;
  const __hip_bfloat16* aR1 = aR0 + (size_t)64 * DMODEL;

  floatx4 acc[3][4][4] = {};

  for (int kt = 0; kt < DMODEL / 32; ++kt) {
    const int k0 = kt * 32;
    stage16(aR0 + k0, lA0);
    stage16(aR1 + k0, lA1);
#pragma unroll
    for (int w = 0; w < 3; ++w) {
      stage16(Wp[w] + (size_t)(n0 + srow) * DMODEL + scol + k0,      Bs[w] + wave * 512);
      stage16(Wp[w] + (size_t)(n0 + 64 + srow) * DMODEL + scol + k0, Bs[w] + 2048 + wave * 512);
    }
    __syncthreads();
    short8 a[4];
#pragma unroll
    for (int i = 0; i < 4; ++i)
      a[i] = *(const short8*)(As + (wm + i * 16 + r) * 32 + quad * 8);
#pragma unroll
    for (int w = 0; w < 3; ++w) {
      short8 b[4];
#pragma unroll
      for (int j = 0; j < 4; ++j)
        b[j] = *(const short8*)(Bs[w] + (wn + j * 16 + r) * 32 + quad * 8);
#pragma unroll
      for (int i = 0; i < 4; ++i)
#pragma unroll
        for (int j = 0; j < 4; ++j)
          acc[w][i][j] = __builtin_amdgcn_mfma_f32_16x16x32_bf16(a[i], b[j], acc[w][i][j], 0, 0, 0);
    }
    __syncthreads();
  }

  // Q, K: row-major stores
  {
    __hip_bfloat16* Op[2] = {Qb, Kb};
    const float* Bp[2] = {bq, bk};
#pragma unroll
    for (int w = 0; w < 2; ++w) {
      __hip_bfloat16* out = Op[w];
#pragma unroll
      for (int j = 0; j < 4; ++j) {
        const int n = n0 + wn + j * 16 + r;
        const float bb = Bp[w][n];
#pragma unroll
        for (int i = 0; i < 4; ++i) {
          const int mbase = m0 + wm + i * 16 + quad * 4;
#pragma unroll
          for (int e = 0; e < 4; ++e)
            out[(size_t)(mbase + e) * DMODEL + n] = __float2bfloat16(acc[w][i][j][e] + bb);
        }
      }
    }
  }
  // V: transposed store Vt[z][d=n][pos], 8B packed per (i,j). z = batch of m0.
  {
    const int z    = m0 >> 11;           // SEQ = 2048
    const int posb = (m0 & (SEQ - 1)) + wm;
    __hip_bfloat16* vt = Vt + (size_t)z * DMODEL * SEQ;
#pragma unroll
    for (int j = 0; j < 4; ++j) {
      const int n = n0 + wn + j * 16 + r;
      const float bb = bv[n];
#pragma unroll
      for (int i = 0; i < 4; ++i) {
        const int pos = posb + i * 16 + quad * 4;
        unsigned long long pk =
            (unsigned long long)bf16_bits(acc[2][i][j][0] + bb)
          | ((unsigned long long)bf16_bits(acc[2][i][j][1] + bb) << 16)
          | ((unsigned long long)bf16_bits(acc[2][i][j][2] + bb) << 32)
          | ((unsigned long long)bf16_bits(acc[2][i][j][3] + bb) << 48);
        *(unsigned long long*)(vt + (size_t)n * SEQ + pos) = pk;
      }
    }
  }
}

// ---------------------------------------------------------------------------
// 2-wave BK=64 GEMM core: C[64x128] += A * B^T, A/B bf16 row-major [.,K].
// 128 threads = 2 waves; wave w owns n-half wn = w*64 (acc[4][4] = 64 AGPR).
// Per k-iter: stage A 64x64 (4 stage16/wave) + B 128x64 (8 stage16/wave),
// one barrier, then 2 x 16 MFMA (kk = 0,1). LDS striped layout (R8, measured
// 0 conflicts): elem (m,k) at (m>>3)*512 + (k>>3)*64 + (m&7)*8 + (k&7);
// staging lane i -> row (i&7), colchunk (i>>3) per 8-row stripe.
// If SUMS: acc_s[i] += A-frag x ones per kk (row sums of A, C-layout, fp32).
template <bool SUMS>
__device__ __forceinline__ void gemm_core_2w64(
    const __hip_bfloat16* __restrict__ A,
    const __hip_bfloat16* __restrict__ B,
    int K, int m0, int n0, int kchunks,
    __hip_bfloat16* As /*64x64 striped*/, __hip_bfloat16* Bs /*128x64 striped*/,
    floatx4 acc[4][4], floatx4 acc_s[4])
{
  const int tid  = threadIdx.x;
  const int lane = tid & 63;
  const int wave = tid >> 6;          // 0..1
  const int quad = lane >> 4;
  const int r    = lane & 15;
  const int wn   = wave * 64;
  const int srow = lane & 7;          // row within 8-row stripe
  const int scol = (lane >> 3) * 8;   // 0..56

  short8 ones;
#pragma unroll
  for (int t = 0; t < 8; ++t) ones[t] = (short)0x3F80;  // bf16 1.0

  // wave w stages A rows [32w,32w+32) (stripes 4w..4w+3) and
  //               B rows [64w,64w+64) (stripes 8w..8w+7)
  const __hip_bfloat16* aB = A + (size_t)(m0 + wave * 32 + srow) * K + scol;
  const __hip_bfloat16* bB = B + (size_t)(n0 + wave * 64 + srow) * K + scol;
  __hip_bfloat16* lA = As + wave * 2048;
  __hip_bfloat16* lB = Bs + wave * 4096;

  for (int kt = 0; kt < kchunks; ++kt) {
    const int k0 = kt * 64;
#pragma unroll
    for (int s = 0; s < 4; ++s)
      stage16(aB + (size_t)(8 * s) * K + k0, lA + s * 512);
#pragma unroll
    for (int s = 0; s < 8; ++s)
      stage16(bB + (size_t)(8 * s) * K + k0, lB + s * 512);
    __syncthreads();
#pragma unroll
    for (int kk = 0; kk < 2; ++kk) {
      short8 a[4], b[4];
      const int kc = kk * 4 + quad;   // colchunk of k = kk*32 + quad*8
#pragma unroll
      for (int i = 0; i < 4; ++i) {
        const int m = i * 16 + r;
        const int n = wn + i * 16 + r;
        a[i] = *(const short8*)(As + (m >> 3) * 512 + kc * 64 + (m & 7) * 8);
        b[i] = *(const short8*)(Bs + (n >> 3) * 512 + kc * 64 + (n & 7) * 8);
      }
      if (SUMS) {
#pragma unroll
        for (int i = 0; i < 4; ++i)
          acc_s[i] = __builtin_amdgcn_mfma_f32_16x16x32_bf16(a[i], ones, acc_s[i], 0, 0, 0);
      }
#pragma unroll
      for (int i = 0; i < 4; ++i)
#pragma unroll
        for (int j = 0; j < 4; ++j)
          acc[i][j] = __builtin_amdgcn_mfma_f32_16x16x32_bf16(a[i], b[j], acc[i][j], 0, 0, 0);
    }
    __syncthreads();
  }
}

// ---------------------------------------------------------------------------
// Scores: P'[z][q][k] = exp((Qb_z Kb_z^T)[q][k]/32) for k<=q (0 in the masked
// part of diagonal tiles), bf16. 64m x 128n tiles, 2-wave blocks, BK=64,
// COMPACT grid: blockIdx.x = linear id over the 272 active (mt,nt) pairs per
// batch. grid = (272, NBATCH), 128 threads, 24 KB LDS.
__global__ __launch_bounds__(128, 4) void gemm_scores(
    const __hip_bfloat16* __restrict__ Qb, const __hip_bfloat16* __restrict__ Kb,
    __hip_bfloat16* __restrict__ Sb)
{
  const int z = blockIdx.y;
  const int L = blockIdx.x;
  // decode pair index p: largest p with p(p+1) <= L
  int p = (int)((sqrtf(4.0f * (float)L + 1.0f) - 1.0f) * 0.5f);
  while ((p + 1) * (p + 2) <= L) ++p;
  while (p * (p + 1) > L) --p;
  const int o  = L - p * (p + 1);          // 0 .. 2p+1
  const int mt = 2 * p + (o > p ? 1 : 0);
  const int nt = (o > p) ? (o - p - 1) : o;
  const int m0 = mt * 64, n0 = nt * 128;

  __shared__ __hip_bfloat16 As[64 * 64], Bs[128 * 64];
  const __hip_bfloat16* A = Qb + (size_t)z * SEQ * DMODEL;
  const __hip_bfloat16* B = Kb + (size_t)z * SEQ * DMODEL;
  __hip_bfloat16* outp = Sb + (size_t)z * SEQ * SEQ;
  floatx4 acc[4][4] = {};
  floatx4 dummy[4];
  gemm_core_2w64<false>(A, B, DMODEL, m0, n0, DMODEL / 64, As, Bs, acc, dummy);

  const int lane = threadIdx.x & 63, wave = threadIdx.x >> 6;
  const int quad = lane >> 4, r = lane & 15;
  const int wn = wave * 64;
  const float scale = 0.03125f;  // 1/sqrt(1024)
#pragma unroll
  for (int i = 0; i < 4; ++i) {
    const int mbase = m0 + i * 16 + quad * 4;
#pragma unroll
    for (int e = 0; e < 4; ++e) {
      const int row = mbase + e;
#pragma unroll
      for (int j = 0; j < 4; ++j) {
        const int n = n0 + wn + j * 16 + r;
        const float pv = (n <= row) ? __expf(acc[i][j][e] * scale) : 0.f;
        outp[(size_t)row * SEQ + n] = __float2bfloat16(pv);
      }
    }
  }
}

// ---------------------------------------------------------------------------
// PV: Out[z][q][d] = (P'_z @ Vt_z^T)[q][d] / rowsum(P'), fp32 out. Row sums
// via the ones-MFMA (acc_s, C-layout). 64m x 128n tiles, 2-wave blocks, BK=64;
// K truncated at the diagonal ((mt+1) chunks); longest-K first.
// grid = (DMODEL/128=8, SEQ/64=32, 4), 128 threads, 24 KB LDS.
__global__ __launch_bounds__(128, 4) void gemm_pv(
    const __hip_bfloat16* __restrict__ Sb, const __hip_bfloat16* __restrict__ Vt,
    float* __restrict__ Out)
{
  __shared__ __hip_bfloat16 As[64 * 64], Bs[128 * 64];
  const int z = blockIdx.z;
  const int mt = (int)gridDim.y - 1 - (int)blockIdx.y;  // longest-first
  const int m0 = mt * 64, n0 = blockIdx.x * 128;
  const __hip_bfloat16* A = Sb + (size_t)z * SEQ * SEQ;
  const __hip_bfloat16* B = Vt + (size_t)z * DMODEL * SEQ;
  float* outp = Out + (size_t)z * SEQ * DMODEL;

  floatx4 acc[4][4] = {};
  floatx4 acc_s[4] = {};
  const int kchunks = mt + 1;   // (m0+64)/64: causal truncation
  gemm_core_2w64<true>(A, B, SEQ, m0, n0, kchunks, As, Bs, acc, acc_s);

  const int lane = threadIdx.x & 63, wave = threadIdx.x >> 6;
  const int quad = lane >> 4, r = lane & 15;
  const int wn = wave * 64;
#pragma unroll
  for (int i = 0; i < 4; ++i) {
    const int mbase = m0 + i * 16 + quad * 4;
    float inv[4];
#pragma unroll
    for (int e = 0; e < 4; ++e) inv[e] = 1.f / acc_s[i][e];
#pragma unroll
    for (int j = 0; j < 4; ++j) {
      const int n = n0 + wn + j * 16 + r;
#pragma unroll
      for (int e = 0; e < 4; ++e)
        outp[(size_t)(mbase + e) * DMODEL + n] = acc[i][j][e] * inv[e];
    }
  }
}

// ---------------------------------------------------------------------------
extern "C" void kernel_launch(void* const* d_in, const int* in_sizes, int n_in,
                              void* d_out, int out_size, void* d_ws, size_t ws_size,
                              hipStream_t stream)
{
  const float* X  = (const float*)d_in[0];
  const float* Wq = (const float*)d_in[1];
  const float* bq = (const float*)d_in[2];
  const float* Wk = (const float*)d_in[3];
  const float* bk = (const float*)d_in[4];
  const float* Wv = (const float*)d_in[5];
  const float* bv = (const float*)d_in[6];
  float* Out = (float*)d_out;

  // Workspace layout (~103 MB total)
  char* ws = (char*)d_ws;
  size_t off = 0;
  auto alloc = [&](size_t bytes) -> void* {
    void* p = ws + off;
    off += (bytes + 255) & ~(size_t)255;
    return p;
  };
  __hip_bfloat16* Xb  = (__hip_bfloat16*)alloc((size_t)MTOT * DMODEL * 2);    // 16 MB
  __hip_bfloat16* Wqb = (__hip_bfloat16*)alloc((size_t)DMODEL * DMODEL * 2);  // 2 MB
  __hip_bfloat16* Wkb = (__hip_bfloat16*)alloc((size_t)DMODEL * DMODEL * 2);
  __hip_bfloat16* Wvb = (__hip_bfloat16*)alloc((size_t)DMODEL * DMODEL * 2);
  __hip_bfloat16* Qb  = (__hip_bfloat16*)alloc((size_t)MTOT * DMODEL * 2);    // 16 MB
  __hip_bfloat16* Kb  = (__hip_bfloat16*)alloc((size_t)MTOT * DMODEL * 2);    // 16 MB
  __hip_bfloat16* Vt  = (__hip_bfloat16*)alloc((size_t)MTOT * DMODEL * 2);    // 16 MB
  __hip_bfloat16* Sb  = (__hip_bfloat16*)alloc((size_t)NBATCH * SEQ * SEQ * 2); // 32 MB
  (void)ws_size; (void)in_sizes; (void)n_in; (void)out_size;

  // 1) converts (one kernel)
  convert_all<<<11264, 256, 0, stream>>>(X, Wq, Wk, Wv, Xb, Wqb, Wkb, Wvb);
  // 2) fused QKV projection (128x128); V written transposed
  gemm_qkv_fused<<<dim3(DMODEL / 128, MTOT / 128), 256, 0, stream>>>(
      Xb, Wqb, Wkb, Wvb, bq, bk, bv, Qb, Kb, Vt);
  // 3) scores: 2-wave BK=64 64x128 tiles, compact grid, P' = exp(s)
  gemm_scores<<<dim3(272, NBATCH), 128, 0, stream>>>(Qb, Kb, Sb);
  // 4) PV: 2-wave BK=64 64x128 tiles, longest-first, in-kernel row sums
  gemm_pv<<<dim3(DMODEL / 128, SEQ / 64, NBATCH), 128, 0, stream>>>(Sb, Vt, Out);
}

// Round 12
// 247.281 us; speedup vs baseline: 1.2434x; 1.2434x over previous
//
#include <hip/hip_runtime.h>
#include <hip/hip_bf16.h>

// Self-attention: q=X@Wq.T+bq, k=..., v=...; S = causal_softmax(q k^T / 32); O = S v
// B=4, S=2048, D_IN=D_OUT=1024. fp32 in/out; internal compute bf16 MFMA + fp32 acc.
//
// R12: exact revert to R10 (best measured: 248.2 us). R11's BK=64 2-wave cores
// regressed (pv 50->96 us: occupancy 11%, FETCH +50%) — fifth confirmation that
// the R9/R10 recipe (BK=32, 2-wave blocks, compact >=1000-block grids) is the
// local optimum for the latency-bound attention GEMMs on this K-loop structure.
// Pipeline: convert_all -> gemm_qkv_fused (128x128, 3-way fused, V stored
// transposed; 780 TF) -> gemm_scores (P'=exp(s), causal, compact triangular
// grid) -> gemm_pv (ones-MFMA row sums in C-layout, normalize in epilogue).
//
// MFMA fragment layouts (HW-verified per guide §3):
//  A: lane holds A[m=lane&15][k=(lane>>4)*8+j], j=0..7
//  B: lane holds B[k=(lane>>4)*8+j][n=lane&15]
//  C/D: lane holds D[row=(lane>>4)*4+e][col=lane&15], e=0..3

typedef __attribute__((ext_vector_type(8))) short short8;   // 8 bf16 = 4 VGPRs
typedef __attribute__((ext_vector_type(4))) float floatx4;  // MFMA acc

#define SEQ   2048
#define DMODEL 1024
#define NBATCH 4
#define MTOT  (SEQ * NBATCH)

// Direct global->LDS async copy, 16B per lane. LDS dst is wave-uniform base +
// lane*16 (per-lane scatter NOT supported).
__device__ __forceinline__ void stage16(const __hip_bfloat16* g, __hip_bfloat16* l)
{
  __builtin_amdgcn_global_load_lds(
      (const __attribute__((address_space(1))) void*)g,
      (__attribute__((address_space(3))) void*)l, 16, 0, 0);
}

__device__ __forceinline__ unsigned short bf16_bits(float f)
{
  __hip_bfloat16 h = __float2bfloat16(f);
  return *(unsigned short*)&h;
}

// ---------------------------------------------------------------------------
// One-kernel fp32 -> bf16 convert for all four inputs. Each block: 1024 elems.
__global__ __launch_bounds__(256) void convert_all(
    const float* __restrict__ X,  const float* __restrict__ Wq,
    const float* __restrict__ Wk, const float* __restrict__ Wv,
    __hip_bfloat16* __restrict__ Xb,  __hip_bfloat16* __restrict__ Wqb,
    __hip_bfloat16* __restrict__ Wkb, __hip_bfloat16* __restrict__ Wvb)
{
  const int b = blockIdx.x;
  const float* src; __hip_bfloat16* dst; int rel;
  if (b < 8192)       { src = X;  dst = Xb;  rel = b; }
  else if (b < 9216)  { src = Wq; dst = Wqb; rel = b - 8192; }
  else if (b < 10240) { src = Wk; dst = Wkb; rel = b - 9216; }
  else                { src = Wv; dst = Wvb; rel = b - 10240; }
  const int i = rel * 1024 + threadIdx.x * 4;
  float4 f = *(const float4*)(src + i);
  uint2 o;
  o.x = (unsigned)bf16_bits(f.x) | ((unsigned)bf16_bits(f.y) << 16);
  o.y = (unsigned)bf16_bits(f.z) | ((unsigned)bf16_bits(f.w) << 16);
  *(uint2*)(dst + i) = o;
}

// ---------------------------------------------------------------------------
// Fused QKV projection (R4 version, best measured). A-tile (X) staged once per
// k-iter, three 128x32 B-tiles; 48 MFMA/wave/barrier. Q,K row-major; V -> Vt.
// grid = (8, 64), 256 threads, 32 KB LDS.
__global__ __launch_bounds__(256, 2) void gemm_qkv_fused(
    const __hip_bfloat16* __restrict__ Xb,
    const __hip_bfloat16* __restrict__ Wqb,
    const __hip_bfloat16* __restrict__ Wkb,
    const __hip_bfloat16* __restrict__ Wvb,
    const float* __restrict__ bq, const float* __restrict__ bk, const float* __restrict__ bv,
    __hip_bfloat16* __restrict__ Qb, __hip_bfloat16* __restrict__ Kb, __hip_bfloat16* __restrict__ Vt)
{
  __shared__ __hip_bfloat16 As[128 * 32];
  __shared__ __hip_bfloat16 Bs[3][128 * 32];
  const int m0 = blockIdx.y * 128, n0 = blockIdx.x * 128;
  const int tid  = threadIdx.x;
  const int lane = tid & 63;
  const int wave = tid >> 6;
  const int quad = lane >> 4;
  const int r    = lane & 15;
  const int wm   = (wave >> 1) * 64;
  const int wn   = (wave & 1) * 64;
  const int srow = wave * 16 + (lane >> 2);   // 0..63
  const int scol = (lane & 3) * 8;            // 0,8,16,24

  const __hip_bfloat16* Wp[3] = {Wqb, Wkb, Wvb};

  __hip_bfloat16* lA0 = As + wave * 512;
  __hip_bfloat16* lA1 = As + 2048 + wave * 512;

  const __hip_bfloat16* aR0 = Xb + (size_t)(m0 + srow) * DMODEL + scol;
  const __hip_bfloat16* aR1 = aR0 + (size_t)64 * DMODEL;

  floatx4 acc[3][4][4] = {};

  for (int kt = 0; kt < DMODEL / 32; ++kt) {
    const int k0 = kt * 32;
    stage16(aR0 + k0, lA0);
    stage16(aR1 + k0, lA1);
#pragma unroll
    for (int w = 0; w < 3; ++w) {
      stage16(Wp[w] + (size_t)(n0 + srow) * DMODEL + scol + k0,      Bs[w] + wave * 512);
      stage16(Wp[w] + (size_t)(n0 + 64 + srow) * DMODEL + scol + k0, Bs[w] + 2048 + wave * 512);
    }
    __syncthreads();
    short8 a[4];
#pragma unroll
    for (int i = 0; i < 4; ++i)
      a[i] = *(const short8*)(As + (wm + i * 16 + r) * 32 + quad * 8);
#pragma unroll
    for (int w = 0; w < 3; ++w) {
      short8 b[4];
#pragma unroll
      for (int j = 0; j < 4; ++j)
        b[j] = *(const short8*)(Bs[w] + (wn + j * 16 + r) * 32 + quad * 8);
#pragma unroll
      for (int i = 0; i < 4; ++i)
#pragma unroll
        for (int j = 0; j < 4; ++j)
          acc[w][i][j] = __builtin_amdgcn_mfma_f32_16x16x32_bf16(a[i], b[j], acc[w][i][j], 0, 0, 0);
    }
    __syncthreads();
  }

  // Q, K: row-major stores
  {
    __hip_bfloat16* Op[2] = {Qb, Kb};
    const float* Bp[2] = {bq, bk};
#pragma unroll
    for (int w = 0; w < 2; ++w) {
      __hip_bfloat16* out = Op[w];
#pragma unroll
      for (int j = 0; j < 4; ++j) {
        const int n = n0 + wn + j * 16 + r;
        const float bb = Bp[w][n];
#pragma unroll
        for (int i = 0; i < 4; ++i) {
          const int mbase = m0 + wm + i * 16 + quad * 4;
#pragma unroll
          for (int e = 0; e < 4; ++e)
            out[(size_t)(mbase + e) * DMODEL + n] = __float2bfloat16(acc[w][i][j][e] + bb);
        }
      }
    }
  }
  // V: transposed store Vt[z][d=n][pos], 8B packed per (i,j). z = batch of m0.
  {
    const int z    = m0 >> 11;           // SEQ = 2048
    const int posb = (m0 & (SEQ - 1)) + wm;
    __hip_bfloat16* vt = Vt + (size_t)z * DMODEL * SEQ;
#pragma unroll
    for (int j = 0; j < 4; ++j) {
      const int n = n0 + wn + j * 16 + r;
      const float bb = bv[n];
#pragma unroll
      for (int i = 0; i < 4; ++i) {
        const int pos = posb + i * 16 + quad * 4;
        unsigned long long pk =
            (unsigned long long)bf16_bits(acc[2][i][j][0] + bb)
          | ((unsigned long long)bf16_bits(acc[2][i][j][1] + bb) << 16)
          | ((unsigned long long)bf16_bits(acc[2][i][j][2] + bb) << 32)
          | ((unsigned long long)bf16_bits(acc[2][i][j][3] + bb) << 48);
        *(unsigned long long*)(vt + (size_t)n * SEQ + pos) = pk;
      }
    }
  }
}

// ---------------------------------------------------------------------------
// 2-wave GEMM core: C[64x128] += A * B^T, A/B bf16 row-major [.,K], BK=32.
// 128 threads = 2 waves; wave w owns n-half wn = w*64 (acc [4][4] = 64 AGPR).
// If SUMS: also acc_s[i] += A-frag x ones (row sums of A in C-layout, fp32).
template <bool SUMS>
__device__ __forceinline__ void gemm_core_2w(
    const __hip_bfloat16* __restrict__ A,
    const __hip_bfloat16* __restrict__ B,
    int K, int m0, int n0, int kchunks,
    __hip_bfloat16* As /*64x32*/, __hip_bfloat16* Bs /*128x32*/,
    floatx4 acc[4][4], floatx4 acc_s[4])
{
  const int tid  = threadIdx.x;
  const int lane = tid & 63;
  const int wave = tid >> 6;          // 0..1
  const int quad = lane >> 4;
  const int r    = lane & 15;
  const int wn   = wave * 64;
  const int lrow = lane >> 2;         // 0..15
  const int lcol = (lane & 3) * 8;    // 0,8,16,24

  short8 ones;
#pragma unroll
  for (int t = 0; t < 8; ++t) ones[t] = (short)0x3F80;  // bf16 1.0

  const __hip_bfloat16* aB = A + (size_t)(m0 + wave * 32 + lrow) * K + lcol;
  const __hip_bfloat16* bB = B + (size_t)(n0 + wave * 64 + lrow) * K + lcol;
  __hip_bfloat16* lA = As + wave * 1024;   // 2 chunks of 512
  __hip_bfloat16* lB = Bs + wave * 2048;   // 4 chunks of 512

  for (int kt = 0; kt < kchunks; ++kt) {
    const int k0 = kt * 32;
#pragma unroll
    for (int s = 0; s < 2; ++s)
      stage16(aB + (size_t)(16 * s) * K + k0, lA + s * 512);
#pragma unroll
    for (int s = 0; s < 4; ++s)
      stage16(bB + (size_t)(16 * s) * K + k0, lB + s * 512);
    __syncthreads();
    short8 a[4], b[4];
#pragma unroll
    for (int i = 0; i < 4; ++i) {
      a[i] = *(const short8*)(As + (i * 16 + r) * 32 + quad * 8);
      b[i] = *(const short8*)(Bs + (wn + i * 16 + r) * 32 + quad * 8);
    }
    if (SUMS) {
#pragma unroll
      for (int i = 0; i < 4; ++i)
        acc_s[i] = __builtin_amdgcn_mfma_f32_16x16x32_bf16(a[i], ones, acc_s[i], 0, 0, 0);
    }
#pragma unroll
    for (int i = 0; i < 4; ++i)
#pragma unroll
      for (int j = 0; j < 4; ++j)
        acc[i][j] = __builtin_amdgcn_mfma_f32_16x16x32_bf16(a[i], b[j], acc[i][j], 0, 0, 0);
    __syncthreads();
  }
}

// ---------------------------------------------------------------------------
// Scores: P'[z][q][k] = exp((Qb_z Kb_z^T)[q][k]/32) for k<=q (0 in the masked
// part of diagonal tiles), bf16. No row sums here (pv derives them itself).
// 64m x 128n tiles, 2-wave blocks, COMPACT grid: blockIdx.x = linear id over
// the 272 active (mt,nt) pairs per batch. grid = (272, NBATCH), 128 threads.
__global__ __launch_bounds__(128, 4) void gemm_scores(
    const __hip_bfloat16* __restrict__ Qb, const __hip_bfloat16* __restrict__ Kb,
    __hip_bfloat16* __restrict__ Sb)
{
  const int z = blockIdx.y;
  const int L = blockIdx.x;
  // decode pair index p: largest p with p(p+1) <= L
  int p = (int)((sqrtf(4.0f * (float)L + 1.0f) - 1.0f) * 0.5f);
  while ((p + 1) * (p + 2) <= L) ++p;
  while (p * (p + 1) > L) --p;
  const int o  = L - p * (p + 1);          // 0 .. 2p+1
  const int mt = 2 * p + (o > p ? 1 : 0);
  const int nt = (o > p) ? (o - p - 1) : o;
  const int m0 = mt * 64, n0 = nt * 128;

  __shared__ __hip_bfloat16 As[64 * 32], Bs[128 * 32];
  const __hip_bfloat16* A = Qb + (size_t)z * SEQ * DMODEL;
  const __hip_bfloat16* B = Kb + (size_t)z * SEQ * DMODEL;
  __hip_bfloat16* outp = Sb + (size_t)z * SEQ * SEQ;
  floatx4 acc[4][4] = {};
  floatx4 dummy[4];
  gemm_core_2w<false>(A, B, DMODEL, m0, n0, DMODEL / 32, As, Bs, acc, dummy);

  const int lane = threadIdx.x & 63, wave = threadIdx.x >> 6;
  const int quad = lane >> 4, r = lane & 15;
  const int wn = wave * 64;
  const float scale = 0.03125f;  // 1/sqrt(1024)
#pragma unroll
  for (int i = 0; i < 4; ++i) {
    const int mbase = m0 + i * 16 + quad * 4;
#pragma unroll
    for (int e = 0; e < 4; ++e) {
      const int row = mbase + e;
#pragma unroll
      for (int j = 0; j < 4; ++j) {
        const int n = n0 + wn + j * 16 + r;
        const float pv = (n <= row) ? __expf(acc[i][j][e] * scale) : 0.f;
        outp[(size_t)row * SEQ + n] = __float2bfloat16(pv);
      }
    }
  }
}

// ---------------------------------------------------------------------------
// PV: Out[z][q][d] = (P'_z @ Vt_z^T)[q][d] / rowsum(P'), fp32 out.
// Row sums computed in-kernel via the ones-MFMA (acc_s, C-layout: every column
// of acc_s[i] holds sum_k P'[row][k] for row = m0+i*16+quad*4+e).
// 64m x 128n tiles, 2-wave blocks; K truncated at the diagonal; longest-K
// first. grid = (DMODEL/128=8, SEQ/64=32, 4), 128 threads.
__global__ __launch_bounds__(128, 4) void gemm_pv(
    const __hip_bfloat16* __restrict__ Sb, const __hip_bfloat16* __restrict__ Vt,
    float* __restrict__ Out)
{
  __shared__ __hip_bfloat16 As[64 * 32], Bs[128 * 32];
  const int z = blockIdx.z;
  const int mt = (int)gridDim.y - 1 - (int)blockIdx.y;  // longest-first
  const int m0 = mt * 64, n0 = blockIdx.x * 128;
  const __hip_bfloat16* A = Sb + (size_t)z * SEQ * SEQ;
  const __hip_bfloat16* B = Vt + (size_t)z * DMODEL * SEQ;
  float* outp = Out + (size_t)z * SEQ * DMODEL;

  floatx4 acc[4][4] = {};
  floatx4 acc_s[4] = {};
  const int kchunks = 2 * mt + 2;   // (m0+64)/32: causal truncation
  gemm_core_2w<true>(A, B, SEQ, m0, n0, kchunks, As, Bs, acc, acc_s);

  const int lane = threadIdx.x & 63, wave = threadIdx.x >> 6;
  const int quad = lane >> 4, r = lane & 15;
  const int wn = wave * 64;
#pragma unroll
  for (int i = 0; i < 4; ++i) {
    const int mbase = m0 + i * 16 + quad * 4;
    float inv[4];
#pragma unroll
    for (int e = 0; e < 4; ++e) inv[e] = 1.f / acc_s[i][e];
#pragma unroll
    for (int j = 0; j < 4; ++j) {
      const int n = n0 + wn + j * 16 + r;
#pragma unroll
      for (int e = 0; e < 4; ++e)
        outp[(size_t)(mbase + e) * DMODEL + n] = acc[i][j][e] * inv[e];
    }
  }
}

// ---------------------------------------------------------------------------
extern "C" void kernel_launch(void* const* d_in, const int* in_sizes, int n_in,
                              void* d_out, int out_size, void* d_ws, size_t ws_size,
                              hipStream_t stream)
{
  const float* X  = (const float*)d_in[0];
  const float* Wq = (const float*)d_in[1];
  const float* bq = (const float*)d_in[2];
  const float* Wk = (const float*)d_in[3];
  const float* bk = (const float*)d_in[4];
  const float* Wv = (const float*)d_in[5];
  const float* bv = (const float*)d_in[6];
  float* Out = (float*)d_out;

  // Workspace layout (~103 MB total)
  char* ws = (char*)d_ws;
  size_t off = 0;
  auto alloc = [&](size_t bytes) -> void* {
    void* p = ws + off;
    off += (bytes + 255) & ~(size_t)255;
    return p;
  };
  __hip_bfloat16* Xb  = (__hip_bfloat16*)alloc((size_t)MTOT * DMODEL * 2);    // 16 MB
  __hip_bfloat16* Wqb = (__hip_bfloat16*)alloc((size_t)DMODEL * DMODEL * 2);  // 2 MB
  __hip_bfloat16* Wkb = (__hip_bfloat16*)alloc((size_t)DMODEL * DMODEL * 2);
  __hip_bfloat16* Wvb = (__hip_bfloat16*)alloc((size_t)DMODEL * DMODEL * 2);
  __hip_bfloat16* Qb  = (__hip_bfloat16*)alloc((size_t)MTOT * DMODEL * 2);    // 16 MB
  __hip_bfloat16* Kb  = (__hip_bfloat16*)alloc((size_t)MTOT * DMODEL * 2);    // 16 MB
  __hip_bfloat16* Vt  = (__hip_bfloat16*)alloc((size_t)MTOT * DMODEL * 2);    // 16 MB
  __hip_bfloat16* Sb  = (__hip_bfloat16*)alloc((size_t)NBATCH * SEQ * SEQ * 2); // 32 MB
  (void)ws_size; (void)in_sizes; (void)n_in; (void)out_size;

  // 1) converts (one kernel)
  convert_all<<<11264, 256, 0, stream>>>(X, Wq, Wk, Wv, Xb, Wqb, Wkb, Wvb);
  // 2) fused QKV projection (128x128); V written transposed
  gemm_qkv_fused<<<dim3(DMODEL / 128, MTOT / 128), 256, 0, stream>>>(
      Xb, Wqb, Wkb, Wvb, bq, bk, bv, Qb, Kb, Vt);
  // 3) scores: 2-wave 64x128 tiles, compact grid, P' = exp(s)
  gemm_scores<<<dim3(272, NBATCH), 128, 0, stream>>>(Qb, Kb, Sb);
  // 4) PV: 2-wave 64x128 tiles, longest-first, in-kernel row sums + normalize
  gemm_pv<<<dim3(DMODEL / 128, SEQ / 64, NBATCH), 128, 0, stream>>>(Sb, Vt, Out);
}

// Round 13
// 233.547 us; speedup vs baseline: 1.3166x; 1.0588x over previous
//
#include <hip/hip_runtime.h>
#include <hip/hip_bf16.h>
#include <hip/hip_fp8.h>

// Self-attention: q=X@Wq.T+bq, k=..., v=...; S = causal_softmax(q k^T / 32); O = S v
// B=4, S=2048, D_IN=D_OUT=1024. fp32 in/out; internal bf16/fp8 MFMA + fp32 acc.
//
// R13 change: scores QK^T goes fp8 e4m3. Q,K stored as e4m3 by the qkv
// epilogue; the scores core keeps the EXACT byte-level tile geometry of the
// working R10 bf16 core (64 B rows, 6 stage16/iter, b128 ds_reads at
// row*64+quad*16) but each tile now carries K=64 -> barrier count HALVED,
// 32 MFMA/wave/barrier. This removes both confounds of R11's failed BK=64-bf16
// (2x staging bytes + new access pattern). k within each 16B group is permuted
// vs the MFMA native mapping — harmless, since A and B share the permutation
// (dot products are k-permutation invariant).
// Precision scope: V and P' stay bf16 (single-key rows pass v through verbatim;
// e4m3's ~4% rel error on v would blow the threshold). Q/K e4m3 error on
// s_scaled ~0.007 -> P rel err ~0.7% -> negligible.
// pv (bf16, ones-MFMA row sums) and qkv K-loop unchanged from R12.
//
// MFMA fragment layouts (HW-verified per guide §3):
//  A: lane holds A[m=lane&15][k=(lane>>4)*8+j], j=0..7
//  B: lane holds B[k=(lane>>4)*8+j][n=lane&15]
//  C/D: lane holds D[row=(lane>>4)*4+e][col=lane&15], e=0..3

typedef __attribute__((ext_vector_type(8))) short short8;   // 8 bf16 = 4 VGPRs
typedef __attribute__((ext_vector_type(4))) float floatx4;  // MFMA acc
typedef __attribute__((ext_vector_type(2))) long longx2;    // 16B = 2 fp8 frags

#define SEQ   2048
#define DMODEL 1024
#define NBATCH 4
#define MTOT  (SEQ * NBATCH)

// Direct global->LDS async copy, 16B per lane. LDS dst is wave-uniform base +
// lane*16 (per-lane scatter NOT supported).
__device__ __forceinline__ void stage16(const void* g, void* l)
{
  __builtin_amdgcn_global_load_lds(
      (const __attribute__((address_space(1))) void*)g,
      (__attribute__((address_space(3))) void*)l, 16, 0, 0);
}

__device__ __forceinline__ unsigned short bf16_bits(float f)
{
  __hip_bfloat16 h = __float2bfloat16(f);
  return *(unsigned short*)&h;
}

__device__ __forceinline__ unsigned char fp8_bits(float f)
{
  __hip_fp8_e4m3 h(f);            // OCP e4m3 (gfx950), not fnuz
  return h.__x;
}

// ---------------------------------------------------------------------------
// One-kernel fp32 -> bf16 convert for all four inputs. Each block: 1024 elems.
__global__ __launch_bounds__(256) void convert_all(
    const float* __restrict__ X,  const float* __restrict__ Wq,
    const float* __restrict__ Wk, const float* __restrict__ Wv,
    __hip_bfloat16* __restrict__ Xb,  __hip_bfloat16* __restrict__ Wqb,
    __hip_bfloat16* __restrict__ Wkb, __hip_bfloat16* __restrict__ Wvb)
{
  const int b = blockIdx.x;
  const float* src; __hip_bfloat16* dst; int rel;
  if (b < 8192)       { src = X;  dst = Xb;  rel = b; }
  else if (b < 9216)  { src = Wq; dst = Wqb; rel = b - 8192; }
  else if (b < 10240) { src = Wk; dst = Wkb; rel = b - 9216; }
  else                { src = Wv; dst = Wvb; rel = b - 10240; }
  const int i = rel * 1024 + threadIdx.x * 4;
  float4 f = *(const float4*)(src + i);
  uint2 o;
  o.x = (unsigned)bf16_bits(f.x) | ((unsigned)bf16_bits(f.y) << 16);
  o.y = (unsigned)bf16_bits(f.z) | ((unsigned)bf16_bits(f.w) << 16);
  *(uint2*)(dst + i) = o;
}

// ---------------------------------------------------------------------------
// Fused QKV projection (R4 K-loop, best measured). A-tile (X) staged once per
// k-iter, three 128x32 B-tiles; 48 MFMA/wave/barrier. Q,K stored as fp8 e4m3
// row-major (for the fp8 scores core); V stored bf16 transposed to Vt.
// grid = (8, 64), 256 threads, 32 KB LDS.
__global__ __launch_bounds__(256, 2) void gemm_qkv_fused(
    const __hip_bfloat16* __restrict__ Xb,
    const __hip_bfloat16* __restrict__ Wqb,
    const __hip_bfloat16* __restrict__ Wkb,
    const __hip_bfloat16* __restrict__ Wvb,
    const float* __restrict__ bq, const float* __restrict__ bk, const float* __restrict__ bv,
    unsigned char* __restrict__ Qb, unsigned char* __restrict__ Kb,
    __hip_bfloat16* __restrict__ Vt)
{
  __shared__ __hip_bfloat16 As[128 * 32];
  __shared__ __hip_bfloat16 Bs[3][128 * 32];
  const int m0 = blockIdx.y * 128, n0 = blockIdx.x * 128;
  const int tid  = threadIdx.x;
  const int lane = tid & 63;
  const int wave = tid >> 6;
  const int quad = lane >> 4;
  const int r    = lane & 15;
  const int wm   = (wave >> 1) * 64;
  const int wn   = (wave & 1) * 64;
  const int srow = wave * 16 + (lane >> 2);   // 0..63
  const int scol = (lane & 3) * 8;            // 0,8,16,24

  const __hip_bfloat16* Wp[3] = {Wqb, Wkb, Wvb};

  __hip_bfloat16* lA0 = As + wave * 512;
  __hip_bfloat16* lA1 = As + 2048 + wave * 512;

  const __hip_bfloat16* aR0 = Xb + (size_t)(m0 + srow) * DMODEL + scol;
  const __hip_bfloat16* aR1 = aR0 + (size_t)64 * DMODEL;

  floatx4 acc[3][4][4] = {};

  for (int kt = 0; kt < DMODEL / 32; ++kt) {
    const int k0 = kt * 32;
    stage16(aR0 + k0, lA0);
    stage16(aR1 + k0, lA1);
#pragma unroll
    for (int w = 0; w < 3; ++w) {
      stage16(Wp[w] + (size_t)(n0 + srow) * DMODEL + scol + k0,      Bs[w] + wave * 512);
      stage16(Wp[w] + (size_t)(n0 + 64 + srow) * DMODEL + scol + k0, Bs[w] + 2048 + wave * 512);
    }
    __syncthreads();
    short8 a[4];
#pragma unroll
    for (int i = 0; i < 4; ++i)
      a[i] = *(const short8*)(As + (wm + i * 16 + r) * 32 + quad * 8);
#pragma unroll
    for (int w = 0; w < 3; ++w) {
      short8 b[4];
#pragma unroll
      for (int j = 0; j < 4; ++j)
        b[j] = *(const short8*)(Bs[w] + (wn + j * 16 + r) * 32 + quad * 8);
#pragma unroll
      for (int i = 0; i < 4; ++i)
#pragma unroll
        for (int j = 0; j < 4; ++j)
          acc[w][i][j] = __builtin_amdgcn_mfma_f32_16x16x32_bf16(a[i], b[j], acc[w][i][j], 0, 0, 0);
    }
    __syncthreads();
  }

  // Q, K: fp8 e4m3 row-major stores
  {
    unsigned char* Op[2] = {Qb, Kb};
    const float* Bp[2] = {bq, bk};
#pragma unroll
    for (int w = 0; w < 2; ++w) {
      unsigned char* out = Op[w];
#pragma unroll
      for (int j = 0; j < 4; ++j) {
        const int n = n0 + wn + j * 16 + r;
        const float bb = Bp[w][n];
#pragma unroll
        for (int i = 0; i < 4; ++i) {
          const int mbase = m0 + wm + i * 16 + quad * 4;
#pragma unroll
          for (int e = 0; e < 4; ++e)
            out[(size_t)(mbase + e) * DMODEL + n] = fp8_bits(acc[w][i][j][e] + bb);
        }
      }
    }
  }
  // V: transposed bf16 store Vt[z][d=n][pos], 8B packed per (i,j).
  {
    const int z    = m0 >> 11;           // SEQ = 2048
    const int posb = (m0 & (SEQ - 1)) + wm;
    __hip_bfloat16* vt = Vt + (size_t)z * DMODEL * SEQ;
#pragma unroll
    for (int j = 0; j < 4; ++j) {
      const int n = n0 + wn + j * 16 + r;
      const float bb = bv[n];
#pragma unroll
      for (int i = 0; i < 4; ++i) {
        const int pos = posb + i * 16 + quad * 4;
        unsigned long long pk =
            (unsigned long long)bf16_bits(acc[2][i][j][0] + bb)
          | ((unsigned long long)bf16_bits(acc[2][i][j][1] + bb) << 16)
          | ((unsigned long long)bf16_bits(acc[2][i][j][2] + bb) << 32)
          | ((unsigned long long)bf16_bits(acc[2][i][j][3] + bb) << 48);
        *(unsigned long long*)(vt + (size_t)n * SEQ + pos) = pk;
      }
    }
  }
}

// ---------------------------------------------------------------------------
// 2-wave fp8 GEMM core: C[64x128] += A * B^T, A/B e4m3 row-major [.,K], BK=64.
// Byte-identical tile geometry to the R10 bf16 core (64 B rows, 6 stage16/iter,
// 12 KB LDS, b128 ds_reads at row*64+quad*16) but 2x K per barrier:
// each 16B register pair = 2 fp8 A/B-frags (kk=0,1) -> 32 MFMA/wave/barrier.
// k within a 16B group is permuted vs native MFMA order — consistent for A and
// B, so the accumulated dot product is exact.
__device__ __forceinline__ void gemm_core_2w_fp8(
    const unsigned char* __restrict__ A,
    const unsigned char* __restrict__ B,
    int K, int m0, int n0, int kchunks,
    unsigned char* As /*64x64B*/, unsigned char* Bs /*128x64B*/,
    floatx4 acc[4][4])
{
  const int tid  = threadIdx.x;
  const int lane = tid & 63;
  const int wave = tid >> 6;          // 0..1
  const int quad = lane >> 4;
  const int r    = lane & 15;
  const int wn   = wave * 64;
  const int lrow = lane >> 2;         // 0..15
  const int lcol = (lane & 3) * 16;   // byte col 0,16,32,48

  const unsigned char* aB = A + (size_t)(m0 + wave * 32 + lrow) * K + lcol;
  const unsigned char* bB = B + (size_t)(n0 + wave * 64 + lrow) * K + lcol;
  unsigned char* lA = As + wave * 2048;   // 2 chunks of 1024 B
  unsigned char* lB = Bs + wave * 4096;   // 4 chunks of 1024 B

  for (int kt = 0; kt < kchunks; ++kt) {
    const int k0 = kt * 64;
#pragma unroll
    for (int s = 0; s < 2; ++s)
      stage16(aB + (size_t)(16 * s) * K + k0, lA + s * 1024);
#pragma unroll
    for (int s = 0; s < 4; ++s)
      stage16(bB + (size_t)(16 * s) * K + k0, lB + s * 1024);
    __syncthreads();
    longx2 a[4], b[4];
#pragma unroll
    for (int i = 0; i < 4; ++i) {
      a[i] = __builtin_bit_cast(longx2, *(const int4*)(As + (i * 16 + r) * 64 + quad * 16));
      b[i] = __builtin_bit_cast(longx2, *(const int4*)(Bs + (wn + i * 16 + r) * 64 + quad * 16));
    }
#pragma unroll
    for (int kk = 0; kk < 2; ++kk)
#pragma unroll
      for (int i = 0; i < 4; ++i)
#pragma unroll
        for (int j = 0; j < 4; ++j)
          acc[i][j] = __builtin_amdgcn_mfma_f32_16x16x32_fp8_fp8(
              a[i][kk], b[j][kk], acc[i][j], 0, 0, 0);
    __syncthreads();
  }
}

// ---------------------------------------------------------------------------
// 2-wave bf16 GEMM core (R10, unchanged): C[64x128] += A * B^T, BK=32.
// If SUMS: also acc_s[i] += A-frag x ones (row sums of A in C-layout, fp32).
template <bool SUMS>
__device__ __forceinline__ void gemm_core_2w(
    const __hip_bfloat16* __restrict__ A,
    const __hip_bfloat16* __restrict__ B,
    int K, int m0, int n0, int kchunks,
    __hip_bfloat16* As /*64x32*/, __hip_bfloat16* Bs /*128x32*/,
    floatx4 acc[4][4], floatx4 acc_s[4])
{
  const int tid  = threadIdx.x;
  const int lane = tid & 63;
  const int wave = tid >> 6;          // 0..1
  const int quad = lane >> 4;
  const int r    = lane & 15;
  const int wn   = wave * 64;
  const int lrow = lane >> 2;         // 0..15
  const int lcol = (lane & 3) * 8;    // 0,8,16,24

  short8 ones;
#pragma unroll
  for (int t = 0; t < 8; ++t) ones[t] = (short)0x3F80;  // bf16 1.0

  const __hip_bfloat16* aB = A + (size_t)(m0 + wave * 32 + lrow) * K + lcol;
  const __hip_bfloat16* bB = B + (size_t)(n0 + wave * 64 + lrow) * K + lcol;
  __hip_bfloat16* lA = As + wave * 1024;   // 2 chunks of 512
  __hip_bfloat16* lB = Bs + wave * 2048;   // 4 chunks of 512

  for (int kt = 0; kt < kchunks; ++kt) {
    const int k0 = kt * 32;
#pragma unroll
    for (int s = 0; s < 2; ++s)
      stage16(aB + (size_t)(16 * s) * K + k0, lA + s * 512);
#pragma unroll
    for (int s = 0; s < 4; ++s)
      stage16(bB + (size_t)(16 * s) * K + k0, lB + s * 512);
    __syncthreads();
    short8 a[4], b[4];
#pragma unroll
    for (int i = 0; i < 4; ++i) {
      a[i] = *(const short8*)(As + (i * 16 + r) * 32 + quad * 8);
      b[i] = *(const short8*)(Bs + (wn + i * 16 + r) * 32 + quad * 8);
    }
    if (SUMS) {
#pragma unroll
      for (int i = 0; i < 4; ++i)
        acc_s[i] = __builtin_amdgcn_mfma_f32_16x16x32_bf16(a[i], ones, acc_s[i], 0, 0, 0);
    }
#pragma unroll
    for (int i = 0; i < 4; ++i)
#pragma unroll
      for (int j = 0; j < 4; ++j)
        acc[i][j] = __builtin_amdgcn_mfma_f32_16x16x32_bf16(a[i], b[j], acc[i][j], 0, 0, 0);
    __syncthreads();
  }
}

// ---------------------------------------------------------------------------
// Scores: P'[z][q][k] = exp((Q_z K_z^T)[q][k]/32) for k<=q (0 in the masked
// part of diagonal tiles), stored bf16. Q,K are fp8 e4m3; BK=64 fp8 core.
// 64m x 128n tiles, 2-wave blocks, COMPACT grid: blockIdx.x = linear id over
// the 272 active (mt,nt) pairs per batch. grid = (272, NBATCH), 128 threads.
__global__ __launch_bounds__(128, 4) void gemm_scores(
    const unsigned char* __restrict__ Qb, const unsigned char* __restrict__ Kb,
    __hip_bfloat16* __restrict__ Sb)
{
  const int z = blockIdx.y;
  const int L = blockIdx.x;
  // decode pair index p: largest p with p(p+1) <= L
  int p = (int)((sqrtf(4.0f * (float)L + 1.0f) - 1.0f) * 0.5f);
  while ((p + 1) * (p + 2) <= L) ++p;
  while (p * (p + 1) > L) --p;
  const int o  = L - p * (p + 1);          // 0 .. 2p+1
  const int mt = 2 * p + (o > p ? 1 : 0);
  const int nt = (o > p) ? (o - p - 1) : o;
  const int m0 = mt * 64, n0 = nt * 128;

  __shared__ unsigned char As[64 * 64], Bs[128 * 64];
  const unsigned char* A = Qb + (size_t)z * SEQ * DMODEL;
  const unsigned char* B = Kb + (size_t)z * SEQ * DMODEL;
  __hip_bfloat16* outp = Sb + (size_t)z * SEQ * SEQ;
  floatx4 acc[4][4] = {};
  gemm_core_2w_fp8(A, B, DMODEL, m0, n0, DMODEL / 64, As, Bs, acc);

  const int lane = threadIdx.x & 63, wave = threadIdx.x >> 6;
  const int quad = lane >> 4, r = lane & 15;
  const int wn = wave * 64;
  const float scale = 0.03125f;  // 1/sqrt(1024)
#pragma unroll
  for (int i = 0; i < 4; ++i) {
    const int mbase = m0 + i * 16 + quad * 4;
#pragma unroll
    for (int e = 0; e < 4; ++e) {
      const int row = mbase + e;
#pragma unroll
      for (int j = 0; j < 4; ++j) {
        const int n = n0 + wn + j * 16 + r;
        const float pv = (n <= row) ? __expf(acc[i][j][e] * scale) : 0.f;
        outp[(size_t)row * SEQ + n] = __float2bfloat16(pv);
      }
    }
  }
}

// ---------------------------------------------------------------------------
// PV: Out[z][q][d] = (P'_z @ Vt_z^T)[q][d] / rowsum(P'), fp32 out.
// Row sums via the ones-MFMA (acc_s, C-layout). 64m x 128n tiles, 2-wave
// blocks, bf16 BK=32 core; K truncated at the diagonal; longest-K first.
// grid = (DMODEL/128=8, SEQ/64=32, 4), 128 threads.
__global__ __launch_bounds__(128, 4) void gemm_pv(
    const __hip_bfloat16* __restrict__ Sb, const __hip_bfloat16* __restrict__ Vt,
    float* __restrict__ Out)
{
  __shared__ __hip_bfloat16 As[64 * 32], Bs[128 * 32];
  const int z = blockIdx.z;
  const int mt = (int)gridDim.y - 1 - (int)blockIdx.y;  // longest-first
  const int m0 = mt * 64, n0 = blockIdx.x * 128;
  const __hip_bfloat16* A = Sb + (size_t)z * SEQ * SEQ;
  const __hip_bfloat16* B = Vt + (size_t)z * DMODEL * SEQ;
  float* outp = Out + (size_t)z * SEQ * DMODEL;

  floatx4 acc[4][4] = {};
  floatx4 acc_s[4] = {};
  const int kchunks = 2 * mt + 2;   // (m0+64)/32: causal truncation
  gemm_core_2w<true>(A, B, SEQ, m0, n0, kchunks, As, Bs, acc, acc_s);

  const int lane = threadIdx.x & 63, wave = threadIdx.x >> 6;
  const int quad = lane >> 4, r = lane & 15;
  const int wn = wave * 64;
#pragma unroll
  for (int i = 0; i < 4; ++i) {
    const int mbase = m0 + i * 16 + quad * 4;
    float inv[4];
#pragma unroll
    for (int e = 0; e < 4; ++e) inv[e] = 1.f / acc_s[i][e];
#pragma unroll
    for (int j = 0; j < 4; ++j) {
      const int n = n0 + wn + j * 16 + r;
#pragma unroll
      for (int e = 0; e < 4; ++e)
        outp[(size_t)(mbase + e) * DMODEL + n] = acc[i][j][e] * inv[e];
    }
  }
}

// ---------------------------------------------------------------------------
extern "C" void kernel_launch(void* const* d_in, const int* in_sizes, int n_in,
                              void* d_out, int out_size, void* d_ws, size_t ws_size,
                              hipStream_t stream)
{
  const float* X  = (const float*)d_in[0];
  const float* Wq = (const float*)d_in[1];
  const float* bq = (const float*)d_in[2];
  const float* Wk = (const float*)d_in[3];
  const float* bk = (const float*)d_in[4];
  const float* Wv = (const float*)d_in[5];
  const float* bv = (const float*)d_in[6];
  float* Out = (float*)d_out;

  // Workspace layout (~87 MB total)
  char* ws = (char*)d_ws;
  size_t off = 0;
  auto alloc = [&](size_t bytes) -> void* {
    void* p = ws + off;
    off += (bytes + 255) & ~(size_t)255;
    return p;
  };
  __hip_bfloat16* Xb  = (__hip_bfloat16*)alloc((size_t)MTOT * DMODEL * 2);    // 16 MB
  __hip_bfloat16* Wqb = (__hip_bfloat16*)alloc((size_t)DMODEL * DMODEL * 2);  // 2 MB
  __hip_bfloat16* Wkb = (__hip_bfloat16*)alloc((size_t)DMODEL * DMODEL * 2);
  __hip_bfloat16* Wvb = (__hip_bfloat16*)alloc((size_t)DMODEL * DMODEL * 2);
  unsigned char*  Qb  = (unsigned char*)alloc((size_t)MTOT * DMODEL);         // 8 MB (fp8)
  unsigned char*  Kb  = (unsigned char*)alloc((size_t)MTOT * DMODEL);         // 8 MB (fp8)
  __hip_bfloat16* Vt  = (__hip_bfloat16*)alloc((size_t)MTOT * DMODEL * 2);    // 16 MB
  __hip_bfloat16* Sb  = (__hip_bfloat16*)alloc((size_t)NBATCH * SEQ * SEQ * 2); // 32 MB
  (void)ws_size; (void)in_sizes; (void)n_in; (void)out_size;

  // 1) converts (one kernel)
  convert_all<<<11264, 256, 0, stream>>>(X, Wq, Wk, Wv, Xb, Wqb, Wkb, Wvb);
  // 2) fused QKV projection; Q,K stored fp8 e4m3, V stored bf16 transposed
  gemm_qkv_fused<<<dim3(DMODEL / 128, MTOT / 128), 256, 0, stream>>>(
      Xb, Wqb, Wkb, Wvb, bq, bk, bv, Qb, Kb, Vt);
  // 3) scores: fp8 BK=64 2-wave core, compact grid, P' = exp(s)
  gemm_scores<<<dim3(272, NBATCH), 128, 0, stream>>>(Qb, Kb, Sb);
  // 4) PV: bf16 2-wave core, longest-first, in-kernel row sums + normalize
  gemm_pv<<<dim3(DMODEL / 128, SEQ / 64, NBATCH), 128, 0, stream>>>(Sb, Vt, Out);
}